// Round 2
// baseline (325.793 us; speedup 1.0000x reference)
//
#include <hip/hip_runtime.h>

// Pure permutation kernel for KernelActivation (k=2), LDS-staged version.
//
// Mapping (verified in prior session):
//   out_flat[ (((b*32+i)*112 + j)*224 + w)*4 + p*2 + q ] = x[b, 2i+p, 2j+q, w]
//
// Strategy: one block per (b, i, j0) tile with TJ=8 j-values.
//  - Load phase: two contiguous 14 KB chunks (16 h-rows x 224 w for c=2i and
//    c=2i+1) staged into LDS with float4 loads -> 16 B/lane, 1 KB per
//    wave-instruction, long sequential DRAM bursts.
//  - Store phase: each thread gathers 4 scalars from LDS (2-way bank aliasing
//    worst case = free) and writes one contiguous float4 of output.
// Both global streams are touched exactly once -> nontemporal.
//
// NOTE: __builtin_nontemporal_* requires a native clang vector type, not
// HIP_vector_type<float,4> — hence the ext_vector_type alias.

typedef float float4n __attribute__((ext_vector_type(4)));

constexpr int Wd = 224;
constexpr int Hd = 224;
constexpr int Cd = 64;
constexpr int HALF_H = Hd / 2;            // 112
constexpr int HALF_C = Cd / 2;            // 32
constexpr int TJ = 8;                     // j-values per block
constexpr int ROWS = 2 * TJ;              // 16 input h-rows per channel chunk
constexpr int CHUNK_F4 = ROWS * Wd / 4;   // 896 float4 per channel chunk
constexpr int TILE_F4 = 2 * CHUNK_F4;     // 1792 float4 staged / emitted
constexpr int BLOCK = 256;

__global__ __launch_bounds__(BLOCK)
void permute_kernel(const float* __restrict__ x, float4n* __restrict__ out) {
    __shared__ float4n lds4[TILE_F4];     // 28 KB
    float* lds = reinterpret_cast<float*>(lds4);

    const int tile = blockIdx.x;
    const int jb = tile % (HALF_H / TJ);  // 0..13
    const int u  = tile / (HALF_H / TJ);
    const int i  = u % HALF_C;
    const int b  = u / HALF_C;
    const int j0 = jb * TJ;

    // Two contiguous input chunks: rows h in [2*j0, 2*j0+ROWS) of channels 2i, 2i+1.
    const float4n* __restrict__ src0 =
        reinterpret_cast<const float4n*>(x + (((size_t)(b * Cd + 2 * i)     * Hd + 2 * j0) * Wd));
    const float4n* __restrict__ src1 =
        reinterpret_cast<const float4n*>(x + (((size_t)(b * Cd + 2 * i + 1) * Hd + 2 * j0) * Wd));

    const int tid = threadIdx.x;

    // ---- Load phase: global -> LDS, float4, fully coalesced.
    // CHUNK_F4 = 896 is a multiple of 64, so no intra-wave divergence on the select.
    #pragma unroll
    for (int t = tid; t < TILE_F4; t += BLOCK) {
        const float4n* __restrict__ s = (t < CHUNK_F4) ? src0 : src1;
        const int r = (t < CHUNK_F4) ? t : (t - CHUNK_F4);
        lds4[t] = __builtin_nontemporal_load(&s[r]);
    }
    __syncthreads();

    // ---- Store phase: LDS gather -> contiguous float4 output.
    // Output tile base: g = ((b*32 + i)*112 + j0)*224
    float4n* __restrict__ dst = out + ((size_t)(b * HALF_C + i) * HALF_H + j0) * Wd;

    #pragma unroll
    for (int t = tid; t < TILE_F4; t += BLOCK) {
        const int jl = t / Wd;            // 0..TJ-1
        const int w  = t % Wd;
        // (p,q) order within the output float4: (0,0),(0,1),(1,0),(1,1)
        float4n v;
        v.x = lds[(2 * jl    ) * Wd + w];           // c=2i,   h=2j
        v.y = lds[(2 * jl + 1) * Wd + w];           // c=2i,   h=2j+1
        v.z = lds[(ROWS + 2 * jl    ) * Wd + w];    // c=2i+1, h=2j
        v.w = lds[(ROWS + 2 * jl + 1) * Wd + w];    // c=2i+1, h=2j+1
        __builtin_nontemporal_store(v, &dst[t]);
    }
}

extern "C" void kernel_launch(void* const* d_in, const int* in_sizes, int n_in,
                              void* d_out, int out_size, void* d_ws, size_t ws_size,
                              hipStream_t stream) {
    const float* x = (const float*)d_in[0];
    float4n* out = (float4n*)d_out;

    const int Bn = out_size / (Cd * Hd * Wd);          // 16
    const int grid = Bn * HALF_C * (HALF_H / TJ);      // 16*32*14 = 7168

    permute_kernel<<<grid, BLOCK, 0, stream>>>(x, out);
}